// Round 1
// baseline (420.199 us; speedup 1.0000x reference)
//
#include <hip/hip_runtime.h>
#include <hip/hip_bf16.h>

// Gate: logits = x[16384,4096] @ W[4096,64]; y = softmax(logits) * top2mask.
// Round 6: BM=32 tokens/WG (512 WGs, 2/CU), depth-3 counted-vmcnt pipeline.
//  - 4 LDS x-buffers; raw s_barrier + asm s_waitcnt vmcnt(8) (never 0 in loop)
//    -> staging loads stay in flight across barriers (T3/T4), ~16KB/CU in flight.
//  - wave w = (token-half h=w>>1, expert-half n2=w&1): only 2 waves share each
//    A-frag -> hi/lo split VALU halved vs round 5.
//  - arithmetic bit-identical to round 5 (same split, same MFMA product order).
//  - logits now written coalesced in the softmax phase.

typedef float f32x4 __attribute__((ext_vector_type(4)));
typedef __bf16 bf16x8 __attribute__((ext_vector_type(8)));

#define MFMA16(a, b, c) __builtin_amdgcn_mfma_f32_16x16x32_bf16((a), (b), (c), 0, 0, 0)

__device__ __forceinline__ void gload_lds16(const void* g, void* l) {
  __builtin_amdgcn_global_load_lds((const __attribute__((address_space(1))) void*)g,
                                   (__attribute__((address_space(3))) void*)l, 16, 0, 0);
}

// ---------------- K1: W pre-pass (1 MB, frag-ready layout) ---------------
// (bit-identical to rounds 4/5) Per chunk c: 4096 elems; half nh at +nh*2048,
// tile ntl at +ntl*1024, hi at +0 / lo at +512, then q*128 + ln*8.
__global__ __launch_bounds__(256) void k_prep_w(const float* __restrict__ W,
                                                __bf16* __restrict__ wsW) {
  const int c = blockIdx.x;       // 0..127
  const int t = threadIdx.x;
  const int e = t & 63;           // expert
  const int q = t >> 6;           // k-quarter
  const int nh = e >> 5, ntl = (e >> 4) & 1, ln = e & 15;
  bf16x8 hi8, lo8;
#pragma unroll
  for (int j = 0; j < 8; ++j) {
    const float w = W[(size_t)(c * 32 + q * 8 + j) * 64 + e];
    const __bf16 h = (__bf16)w;
    hi8[j] = h;
    lo8[j] = (__bf16)(w - (float)h);
  }
  __bf16* base = wsW + (size_t)c * 4096 + nh * 2048 + ntl * 1024 + q * 128 + ln * 8;
  *(bf16x8*)base = hi8;
  *(bf16x8*)(base + 512) = lo8;
}

// exact truncation split (bit-identical to rounds 3/4/5)
__device__ __forceinline__ void split8(const f32x4 a, const f32x4 b,
                                       bf16x8& hi, bf16x8& lo) {
  const float f[8] = {a.x, a.y, a.z, a.w, b.x, b.y, b.z, b.w};
#pragma unroll
  for (int i = 0; i < 8; ++i) {
    const unsigned u = __builtin_bit_cast(unsigned, f[i]);
    hi[i] = __builtin_bit_cast(__bf16, (unsigned short)(u >> 16));
    lo[i] = (__bf16)(f[i] - __builtin_bit_cast(float, u & 0xFFFF0000u));
  }
}

// ---------------- fused gate kernel --------------------------------------
// Grid 512 x 256. WG = 32 tokens; wave w: tokens (w>>1)*16..+15, experts
// (w&1)*32..+31 (2 n-tiles). x LDS: 4 bufs x 4KB; per buf slot s = r*8 + p
// (16-B units), phys group p holds logical k-group g = p ^ (r&7).
// Pipeline per iter c:  s_waitcnt vmcnt(8); s_barrier;  issue W(c+1) (4 L2
// loads) + stage(c+3) (1 global_load_lds/wave);  ds_read A(c); split; 8 MFMA.
// With 5 mem-ops/iter fenced per-iteration, vmcnt(8) leaves at most the
// newest 8 (iters c-1 and tail of c-2) outstanding -> stage(c) provably done,
// stages c+1..c+3 stay in flight across the barrier (no vmcnt(0) drain).
__global__ __launch_bounds__(256, 2) void k_gate(const float* __restrict__ x,
                                                 const __bf16* __restrict__ wsW,
                                                 float* __restrict__ y,
                                                 float* __restrict__ logits) {
  __shared__ __align__(16) char xs[4][4096];
  __shared__ float lt[32 * 65];

  const int t = threadIdx.x, w = t >> 6, l = t & 63;
  const int tb = blockIdx.x * 32;
  const int q = l >> 4, ln = l & 15;
  const int h = w >> 1;         // token half
  const int n2 = w & 1;         // expert half

  // x staging (all 4 waves): wave w stages rows w*8..w*8+7.
  // lane l -> row r = w*8 + (l>>3), phys group l&7, logical g = (l&7)^(r&7);
  // dest slot = w*64 + l (wave-uniform base + lane*16, as gload_lds requires).
  const int sr = w * 8 + (l >> 3);
  const int sg = (l & 7) ^ (sr & 7);
  const float* xp = x + (size_t)(tb + sr) * 4096 + sg * 4;

  // A-frag ds_read offsets: row ar = h*16 + ln, logical groups 2q, 2q+1.
  const int ar = h * 16 + ln;
  const int offA0 = (ar * 8 + ((2 * q) ^ (ar & 7))) * 16;
  const int offA1 = (ar * 8 + ((2 * q + 1) ^ (ar & 7))) * 16;

  // W B-frag global source: expert half n2 -> tiles 2*n2, 2*n2+1.
  // bytes per chunk: 8192; within: tile ntl at +ntl*2048, lo at +1024.
  const char* wgp = (const char*)wsW + n2 * 4096 + q * 256 + ln * 16;

  f32x4 acc0 = {0.f, 0.f, 0.f, 0.f};
  f32x4 acc1 = {0.f, 0.f, 0.f, 0.f};

  // ---- prologue: W(0) into regs; stage chunks 0..2; drain once. ----
  bf16x8 wh0 = *(const bf16x8*)(wgp);
  bf16x8 wl0 = *(const bf16x8*)(wgp + 1024);
  bf16x8 wh1 = *(const bf16x8*)(wgp + 2048);
  bf16x8 wl1 = *(const bf16x8*)(wgp + 3072);
  gload_lds16(xp, &xs[0][(w * 64 + l) * 16]);
  gload_lds16(xp + 32, &xs[1][(w * 64 + l) * 16]);
  gload_lds16(xp + 64, &xs[2][(w * 64 + l) * 16]);
  asm volatile("s_waitcnt vmcnt(0)" ::: "memory");

  for (int c = 0; c < 128; ++c) {
    // stage(c) is guaranteed complete for every wave after this wait+barrier
    // (vmcnt(8) leaves only the newest 8 of the <=15 outstanding mem ops).
    asm volatile("s_waitcnt vmcnt(8)" ::: "memory");
    __builtin_amdgcn_s_barrier();
    __builtin_amdgcn_sched_barrier(0);

    // next-chunk W frags (L2-hot) + depth-3 x staging
    const int cn = (c + 1 < 128) ? (c + 1) : 127;
    const char* wp = wgp + (size_t)cn * 8192;
    bf16x8 nh0 = *(const bf16x8*)(wp);
    bf16x8 nl0 = *(const bf16x8*)(wp + 1024);
    bf16x8 nh1 = *(const bf16x8*)(wp + 2048);
    bf16x8 nl1 = *(const bf16x8*)(wp + 3072);
    if (c + 3 < 128)
      gload_lds16(xp + (size_t)(c + 3) * 32, &xs[(c + 3) & 3][(w * 64 + l) * 16]);

    const char* xb = xs[c & 3];
    const f32x4 A = *(const f32x4*)(xb + offA0);
    const f32x4 B = *(const f32x4*)(xb + offA1);
    bf16x8 ah, al;
    split8(A, B, ah, al);
    acc0 = MFMA16(ah, wh0, acc0);    // same product order as rounds 3/4/5
    acc0 = MFMA16(al, wh0, acc0);
    acc0 = MFMA16(ah, wl0, acc0);
    acc0 = MFMA16(al, wl0, acc0);
    acc1 = MFMA16(ah, wh1, acc1);
    acc1 = MFMA16(al, wh1, acc1);
    acc1 = MFMA16(ah, wl1, acc1);
    acc1 = MFMA16(al, wl1, acc1);
    wh0 = nh0; wl0 = nl0; wh1 = nh1; wl1 = nl1;
    __builtin_amdgcn_sched_barrier(0);  // keep body (incl. MFMA) inside the fences
  }

  // ---------------- epilogue: logits + softmax + top-2 -------------------
  // C/D: lane l, reg r -> row=q*4+r, col=ln. token = h*16+row, expert = n2*32+tile*16+ln.
#pragma unroll
  for (int r = 0; r < 4; ++r) {
    const int tok = h * 16 + q * 4 + r;
    lt[tok * 65 + n2 * 32 + ln] = acc0[r];
    lt[tok * 65 + n2 * 32 + 16 + ln] = acc1[r];
  }
  __syncthreads();

#pragma unroll
  for (int i = 0; i < 8; ++i) {
    const int tok = w * 8 + i;
    const float v = lt[tok * 65 + l];
    float bv = v; int bi = l;
    for (int off = 32; off; off >>= 1) {
      const float ov = __shfl_xor(bv, off);
      const int oi = __shfl_xor(bi, off);
      if (ov > bv || (ov == bv && oi < bi)) { bv = ov; bi = oi; }
    }
    const int i1 = bi;
    const float m1 = bv;
    float cv = (l == i1) ? -3.402823466e38f : v;
    int ci = l;
    for (int off = 32; off; off >>= 1) {
      const float ov = __shfl_xor(cv, off);
      const int oi = __shfl_xor(ci, off);
      if (ov > cv || (ov == cv && oi < ci)) { cv = ov; ci = oi; }
    }
    const float e = __expf(v - m1);
    float s = e;
    for (int off = 32; off; off >>= 1) s += __shfl_xor(s, off);
    logits[(size_t)(tb + tok) * 64 + l] = v;
    y[(size_t)(tb + tok) * 64 + l] = (l == i1 || l == ci) ? (e / s) : 0.0f;
  }
}

// ---------------- launcher ------------------------------------------------
extern "C" void kernel_launch(void* const* d_in, const int* in_sizes, int n_in,
                              void* d_out, int out_size, void* d_ws, size_t ws_size,
                              hipStream_t stream) {
  (void)in_sizes; (void)n_in; (void)out_size; (void)ws_size;
  const float* x = (const float*)d_in[0];
  const float* W = (const float*)d_in[1];
  float* out = (float*)d_out;
  float* yout = out;                 // [16384,64]
  float* logits = out + 1048576;     // [16384,64]
  __bf16* wsW = (__bf16*)d_ws;       // 1 MB frag-ready bf16 hi/lo W

  k_prep_w<<<128, 256, 0, stream>>>(W, wsW);
  k_gate<<<512, 256, 0, stream>>>(x, wsW, yout, logits);
}

// Round 2
// 419.740 us; speedup vs baseline: 1.0011x; 1.0011x over previous
//
#include <hip/hip_runtime.h>
#include <hip/hip_bf16.h>

// Gate: logits = x[16384,4096] @ W[4096,64]; y = softmax(logits) * top2mask.
// Round 7: barrier-free wave-independent K-split GEMM.
//  - WG = 16 tokens, 4 waves; wave w owns K-quarter w (1024 k), ALL 64 experts.
//    1024 WGs -> 4 WG/CU, 16 waves/CU (50% occ), zero barriers in main loop.
//  - A-frags loaded global->reg directly (16 rows x 128B line-aligned per
//    dwordx4 -> 100% line utilization); no LDS staging, no ds_read, no
//    global_load_lds, no manual vmcnt. Compiler schedules all waits.
//  - A prefetch distance 2 (4-slot rotation), W-frag prefetch distance 1
//    (2-slot), full unroll -> all static indices (no scratch).
//  - K-quarter partials summed in-LDS (one __syncthreads), then the
//    round-5 softmax/top-2 epilogue verbatim.
//  - per-product arithmetic identical to rounds 3-6 (same split, same MFMA
//    order); only the 128-chunk accumulation is regrouped 4x32 (+3 f32 adds).

typedef float f32x4 __attribute__((ext_vector_type(4)));
typedef __bf16 bf16x8 __attribute__((ext_vector_type(8)));

#define MFMA16(a, b, c) __builtin_amdgcn_mfma_f32_16x16x32_bf16((a), (b), (c), 0, 0, 0)

// ---------------- K1: W pre-pass (1 MB, frag-ready layout) ---------------
// (bit-identical to rounds 4-6) Per chunk c: 4096 elems; tile T=nh*2+ntl at
// +T*1024 (expert = T*16+ln), hi at +0 / lo at +512, then q*128 + ln*8.
__global__ __launch_bounds__(256) void k_prep_w(const float* __restrict__ W,
                                                __bf16* __restrict__ wsW) {
  const int c = blockIdx.x;       // 0..127
  const int t = threadIdx.x;
  const int e = t & 63;           // expert
  const int q = t >> 6;           // k-quarter
  const int nh = e >> 5, ntl = (e >> 4) & 1, ln = e & 15;
  bf16x8 hi8, lo8;
#pragma unroll
  for (int j = 0; j < 8; ++j) {
    const float w = W[(size_t)(c * 32 + q * 8 + j) * 64 + e];
    const __bf16 h = (__bf16)w;
    hi8[j] = h;
    lo8[j] = (__bf16)(w - (float)h);
  }
  __bf16* base = wsW + (size_t)c * 4096 + nh * 2048 + ntl * 1024 + q * 128 + ln * 8;
  *(bf16x8*)base = hi8;
  *(bf16x8*)(base + 512) = lo8;
}

// exact truncation split (bit-identical to rounds 3-6)
__device__ __forceinline__ void split8(const f32x4 a, const f32x4 b,
                                       bf16x8& hi, bf16x8& lo) {
  const float f[8] = {a.x, a.y, a.z, a.w, b.x, b.y, b.z, b.w};
#pragma unroll
  for (int i = 0; i < 8; ++i) {
    const unsigned u = __builtin_bit_cast(unsigned, f[i]);
    hi[i] = __builtin_bit_cast(__bf16, (unsigned short)(u >> 16));
    lo[i] = (__bf16)(f[i] - __builtin_bit_cast(float, u & 0xFFFF0000u));
  }
}

// ---------------- fused gate kernel --------------------------------------
// Grid 1024 x 256. WG = 16 tokens (tb..tb+15). Wave w: K-quarter w, experts
// 0..63 (4 n-tiles). Per chunk c (32 k): 2 global dwordx4 A-loads (row ln,
// k = w*1024 + c*32 + q*8 + j), 8 W-frag loads (L2-hot), split8, 16 MFMA.
// A-frag: lane l -> A[m=l&15][k=(l>>4)*8+j].  C/D: row=(l>>4)*4+r, col=l&15.
__global__ __launch_bounds__(256, 4) void k_gate(const float* __restrict__ x,
                                                 const __bf16* __restrict__ wsW,
                                                 float* __restrict__ y,
                                                 float* __restrict__ logits) {
  __shared__ float ltp[4][16][65];

  const int t = threadIdx.x, w = t >> 6, l = t & 63;
  const int tb = blockIdx.x * 16;
  const int q = l >> 4, ln = l & 15;

  // A source: row tb+ln, k base = w*1024 + q*8
  const float* xp = x + (size_t)(tb + ln) * 4096 + w * 1024 + q * 8;
  // W frag source for global chunk gc = w*32 + c (bytes):
  //   wgp + gc*8192 + T*2048 (+1024 for lo)
  const char* wgp = (const char*)wsW + (size_t)w * 32 * 8192 + q * 256 + ln * 16;

  f32x4 acc[4] = {{0.f, 0.f, 0.f, 0.f}, {0.f, 0.f, 0.f, 0.f},
                  {0.f, 0.f, 0.f, 0.f}, {0.f, 0.f, 0.f, 0.f}};
  f32x4 abuf[4][2];     // A rotation, prefetch distance 2
  bf16x8 wbuf[2][8];    // W rotation, prefetch distance 1

  auto loadA = [&](int c, int slot) {
    const float* p = xp + (size_t)c * 32;
    abuf[slot][0] = *(const f32x4*)(p);
    abuf[slot][1] = *(const f32x4*)(p + 4);
  };
  auto loadW = [&](int c, int slot) {
    const char* p = wgp + (size_t)c * 8192;
#pragma unroll
    for (int T = 0; T < 4; ++T) {
      wbuf[slot][2 * T] = *(const bf16x8*)(p + T * 2048);
      wbuf[slot][2 * T + 1] = *(const bf16x8*)(p + T * 2048 + 1024);
    }
  };

  // prologue
  loadA(0, 0);
  loadA(1, 1);
  loadW(0, 0);

#pragma unroll
  for (int c = 0; c < 32; ++c) {
    const int ca = (c + 2 < 32) ? c + 2 : 31;   // clamped redundant tail loads
    loadA(ca, (c + 2) & 3);
    const int cw = (c + 1 < 32) ? c + 1 : 31;
    loadW(cw, (c + 1) & 1);
    bf16x8 ah, al;
    split8(abuf[c & 3][0], abuf[c & 3][1], ah, al);
#pragma unroll
    for (int T = 0; T < 4; ++T) {
      const bf16x8 wh = wbuf[c & 1][2 * T];
      const bf16x8 wl = wbuf[c & 1][2 * T + 1];
      acc[T] = MFMA16(ah, wh, acc[T]);   // same product order as rounds 3-6
      acc[T] = MFMA16(al, wh, acc[T]);
      acc[T] = MFMA16(ah, wl, acc[T]);
      acc[T] = MFMA16(al, wl, acc[T]);
    }
  }

  // ---- combine K-quarter partials in LDS (the only barrier) -------------
#pragma unroll
  for (int r = 0; r < 4; ++r)
#pragma unroll
    for (int T = 0; T < 4; ++T)
      ltp[w][q * 4 + r][T * 16 + ln] = acc[T][r];
  __syncthreads();

  // ---------------- softmax + top-2 (round-5 epilogue) -------------------
#pragma unroll
  for (int i = 0; i < 4; ++i) {
    const int tok = w * 4 + i;
    const float v = ltp[0][tok][l] + ltp[1][tok][l] + ltp[2][tok][l] + ltp[3][tok][l];
    float bv = v; int bi = l;
    for (int off = 32; off; off >>= 1) {
      const float ov = __shfl_xor(bv, off);
      const int oi = __shfl_xor(bi, off);
      if (ov > bv || (ov == bv && oi < bi)) { bv = ov; bi = oi; }
    }
    const int i1 = bi;
    const float m1 = bv;
    float cv = (l == i1) ? -3.402823466e38f : v;
    int ci = l;
    for (int off = 32; off; off >>= 1) {
      const float ov = __shfl_xor(cv, off);
      const int oi = __shfl_xor(ci, off);
      if (ov > cv || (ov == cv && oi < ci)) { cv = ov; ci = oi; }
    }
    const float e = __expf(v - m1);
    float s = e;
    for (int off = 32; off; off >>= 1) s += __shfl_xor(s, off);
    logits[(size_t)(tb + tok) * 64 + l] = v;
    y[(size_t)(tb + tok) * 64 + l] = (l == i1 || l == ci) ? (e / s) : 0.0f;
  }
}

// ---------------- launcher ------------------------------------------------
extern "C" void kernel_launch(void* const* d_in, const int* in_sizes, int n_in,
                              void* d_out, int out_size, void* d_ws, size_t ws_size,
                              hipStream_t stream) {
  (void)in_sizes; (void)n_in; (void)out_size; (void)ws_size;
  const float* x = (const float*)d_in[0];
  const float* W = (const float*)d_in[1];
  float* out = (float*)d_out;
  float* yout = out;                 // [16384,64]
  float* logits = out + 1048576;     // [16384,64]
  __bf16* wsW = (__bf16*)d_ws;       // 1 MB frag-ready bf16 hi/lo W

  k_prep_w<<<128, 256, 0, stream>>>(W, wsW);
  k_gate<<<1024, 256, 0, stream>>>(x, wsW, yout, logits);
}

// Round 4
// 402.671 us; speedup vs baseline: 1.0435x; 1.0424x over previous
//
#include <hip/hip_runtime.h>
#include <hip/hip_bf16.h>

// Gate: logits = x[16384,4096] @ W[4096,64]; y = softmax(logits) * top2mask.
// Round 9 == Round 8 resubmit (container infra failure, kernel untested).
// Register-resident deep pipeline, all pipeline slots NAMED variables
// (rule #20: no runtime-indexable arrays -> no scratch, no load sinking).
//  - WG = 32 tokens (2 m-tiles), 4 waves; wave w = K-quarter w, all 64 experts.
//    512 WGs -> 2 WG/CU, 8 waves/CU; zero barriers in main loop.
//  - A: global->reg, prefetch depth 4 chunks (16 dwordx4 = 16 KB/wave in
//    flight); W: depth 2 chunks (L2-hot). #pragma unroll 1 keeps the rolled
//    rotation; all slot names static.
//  - W frags reused by both m-tiles -> W L2 traffic halved vs round 7.
//  - per-product arithmetic bit-identical to rounds 3-7 (same split, same MFMA
//    order, same 4-quarter regroup) -> absmax unchanged.

typedef float f32x4 __attribute__((ext_vector_type(4)));
typedef __bf16 bf16x8 __attribute__((ext_vector_type(8)));

#define MFMA16(a, b, c) __builtin_amdgcn_mfma_f32_16x16x32_bf16((a), (b), (c), 0, 0, 0)

// ---------------- K1: W pre-pass (1 MB, frag-ready layout) ---------------
// (bit-identical to rounds 4-8) Per chunk c: 4096 elems; tile T at +T*1024
// (expert = T*16+ln), hi at +0 / lo at +512, then q*128 + ln*8.
__global__ __launch_bounds__(256) void k_prep_w(const float* __restrict__ W,
                                                __bf16* __restrict__ wsW) {
  const int c = blockIdx.x;       // 0..127
  const int t = threadIdx.x;
  const int e = t & 63;           // expert
  const int q = t >> 6;           // k-quarter
  const int nh = e >> 5, ntl = (e >> 4) & 1, ln = e & 15;
  bf16x8 hi8, lo8;
#pragma unroll
  for (int j = 0; j < 8; ++j) {
    const float w = W[(size_t)(c * 32 + q * 8 + j) * 64 + e];
    const __bf16 h = (__bf16)w;
    hi8[j] = h;
    lo8[j] = (__bf16)(w - (float)h);
  }
  __bf16* base = wsW + (size_t)c * 4096 + nh * 2048 + ntl * 1024 + q * 128 + ln * 8;
  *(bf16x8*)base = hi8;
  *(bf16x8*)(base + 512) = lo8;
}

// exact truncation split (bit-identical to rounds 3-8)
__device__ __forceinline__ void split8(const f32x4 a, const f32x4 b,
                                       bf16x8& hi, bf16x8& lo) {
  const float f[8] = {a.x, a.y, a.z, a.w, b.x, b.y, b.z, b.w};
#pragma unroll
  for (int i = 0; i < 8; ++i) {
    const unsigned u = __builtin_bit_cast(unsigned, f[i]);
    hi[i] = __builtin_bit_cast(__bf16, (unsigned short)(u >> 16));
    lo[i] = (__bf16)(f[i] - __builtin_bit_cast(float, u & 0xFFFF0000u));
  }
}

// A-set load: m-tile0 rows tb+ln, m-tile1 rows tb+16+ln; 2 dwordx4 each.
#define LOADA(Sa0, Sa1, Sb0, Sb1, cc) do {                    \
    const float* _p0 = xp0 + (cc) * 32;                       \
    const float* _p1 = xp1 + (cc) * 32;                       \
    Sa0 = *(const f32x4*)(_p0);                               \
    Sa1 = *(const f32x4*)(_p0 + 4);                           \
    Sb0 = *(const f32x4*)(_p1);                               \
    Sb1 = *(const f32x4*)(_p1 + 4);                           \
  } while (0)

// W-set load: 8 frags (wh/wl for 4 n-tiles), 16 B each, 1 KB apart.
#define LOADW(W0, W1, W2, W3, W4, W5, W6, W7, cc) do {        \
    const char* _p = wgp + (size_t)(cc) * 8192;               \
    W0 = *(const bf16x8*)(_p);                                \
    W1 = *(const bf16x8*)(_p + 1024);                         \
    W2 = *(const bf16x8*)(_p + 2048);                         \
    W3 = *(const bf16x8*)(_p + 3072);                         \
    W4 = *(const bf16x8*)(_p + 4096);                         \
    W5 = *(const bf16x8*)(_p + 5120);                         \
    W6 = *(const bf16x8*)(_p + 6144);                         \
    W7 = *(const bf16x8*)(_p + 7168);                         \
  } while (0)

// One K-chunk: consume A set + W set, re-issue A (depth 4) and W (depth 2).
// MFMA order per (m,T): (ah,wh),(al,wh),(ah,wl),(al,wl) - as rounds 3-8.
#define CHUNK(Sa0, Sa1, Sb0, Sb1, W0, W1, W2, W3, W4, W5, W6, W7, ccA, ccW) do { \
    bf16x8 ah0, al0, ah1, al1;                                \
    split8(Sa0, Sa1, ah0, al0);                               \
    split8(Sb0, Sb1, ah1, al1);                               \
    LOADA(Sa0, Sa1, Sb0, Sb1, ccA);                           \
    c00 = MFMA16(ah0, W0, c00); c00 = MFMA16(al0, W0, c00);   \
    c00 = MFMA16(ah0, W1, c00); c00 = MFMA16(al0, W1, c00);   \
    c01 = MFMA16(ah0, W2, c01); c01 = MFMA16(al0, W2, c01);   \
    c01 = MFMA16(ah0, W3, c01); c01 = MFMA16(al0, W3, c01);   \
    c02 = MFMA16(ah0, W4, c02); c02 = MFMA16(al0, W4, c02);   \
    c02 = MFMA16(ah0, W5, c02); c02 = MFMA16(al0, W5, c02);   \
    c03 = MFMA16(ah0, W6, c03); c03 = MFMA16(al0, W6, c03);   \
    c03 = MFMA16(ah0, W7, c03); c03 = MFMA16(al0, W7, c03);   \
    c10 = MFMA16(ah1, W0, c10); c10 = MFMA16(al1, W0, c10);   \
    c10 = MFMA16(ah1, W1, c10); c10 = MFMA16(al1, W1, c10);   \
    c11 = MFMA16(ah1, W2, c11); c11 = MFMA16(al1, W2, c11);   \
    c11 = MFMA16(ah1, W3, c11); c11 = MFMA16(al1, W3, c11);   \
    c12 = MFMA16(ah1, W4, c12); c12 = MFMA16(al1, W4, c12);   \
    c12 = MFMA16(ah1, W5, c12); c12 = MFMA16(al1, W5, c12);   \
    c13 = MFMA16(ah1, W6, c13); c13 = MFMA16(al1, W6, c13);   \
    c13 = MFMA16(ah1, W7, c13); c13 = MFMA16(al1, W7, c13);   \
    LOADW(W0, W1, W2, W3, W4, W5, W6, W7, ccW);               \
  } while (0)

// ---------------- fused gate kernel --------------------------------------
// Grid 512 x 256. WG = 32 tokens. Wave w: K-quarter w (chunks w*32..w*32+31),
// experts 0..63. A-frag: lane l -> A[m=l&15][k=(l>>4)*8+j].
// C/D: lane l, reg r -> row=(l>>4)*4+r, col=l&15.
__global__ __launch_bounds__(256, 2) void k_gate(const float* __restrict__ x,
                                                 const __bf16* __restrict__ wsW,
                                                 float* __restrict__ y,
                                                 float* __restrict__ logits) {
  __shared__ float ltp[4][32][65];

  const int t = threadIdx.x, w = t >> 6, l = t & 63;
  const int tb = blockIdx.x * 32;
  const int q = l >> 4, ln = l & 15;

  const float* xp0 = x + (size_t)(tb + ln) * 4096 + w * 1024 + q * 8;
  const float* xp1 = xp0 + 16 * 4096;
  const char* wgp = (const char*)wsW + (size_t)w * 32 * 8192 + q * 256 + ln * 16;

  f32x4 c00 = {0.f, 0.f, 0.f, 0.f}, c01 = c00, c02 = c00, c03 = c00;
  f32x4 c10 = c00, c11 = c00, c12 = c00, c13 = c00;

  // named pipeline slots (NO arrays anywhere)
  f32x4 S0a0, S0a1, S0b0, S0b1, S1a0, S1a1, S1b0, S1b1;
  f32x4 S2a0, S2a1, S2b0, S2b1, S3a0, S3a1, S3b0, S3b1;
  bf16x8 Wa0, Wa1, Wa2, Wa3, Wa4, Wa5, Wa6, Wa7;
  bf16x8 Wb0, Wb1, Wb2, Wb3, Wb4, Wb5, Wb6, Wb7;

  // prologue: A chunks 0..3 (16 loads), W chunks 0..1 (16 loads) in flight.
  LOADA(S0a0, S0a1, S0b0, S0b1, 0);
  LOADA(S1a0, S1a1, S1b0, S1b1, 1);
  LOADA(S2a0, S2a1, S2b0, S2b1, 2);
  LOADA(S3a0, S3a1, S3b0, S3b1, 3);
  LOADW(Wa0, Wa1, Wa2, Wa3, Wa4, Wa5, Wa6, Wa7, 0);
  LOADW(Wb0, Wb1, Wb2, Wb3, Wb4, Wb5, Wb6, Wb7, 1);

#pragma unroll 1
  for (int c = 0; c < 32; c += 4) {
    const int a4 = (c + 4 < 32) ? c + 4 : 31;   // clamped redundant tail loads
    const int a5 = (c + 5 < 32) ? c + 5 : 31;
    const int a6 = (c + 6 < 32) ? c + 6 : 31;
    const int a7 = (c + 7 < 32) ? c + 7 : 31;
    const int w2 = (c + 2 < 32) ? c + 2 : 31;
    const int w3 = (c + 3 < 32) ? c + 3 : 31;
    CHUNK(S0a0, S0a1, S0b0, S0b1, Wa0, Wa1, Wa2, Wa3, Wa4, Wa5, Wa6, Wa7, a4, w2);
    CHUNK(S1a0, S1a1, S1b0, S1b1, Wb0, Wb1, Wb2, Wb3, Wb4, Wb5, Wb6, Wb7, a5, w3);
    CHUNK(S2a0, S2a1, S2b0, S2b1, Wa0, Wa1, Wa2, Wa3, Wa4, Wa5, Wa6, Wa7, a6, a4);
    CHUNK(S3a0, S3a1, S3b0, S3b1, Wb0, Wb1, Wb2, Wb3, Wb4, Wb5, Wb6, Wb7, a7, a5);
  }

  // ---- combine K-quarter partials in LDS (the only barrier) -------------
#pragma unroll
  for (int r = 0; r < 4; ++r) {
    const int row = q * 4 + r;
    ltp[w][row][0 * 16 + ln] = c00[r];
    ltp[w][row][1 * 16 + ln] = c01[r];
    ltp[w][row][2 * 16 + ln] = c02[r];
    ltp[w][row][3 * 16 + ln] = c03[r];
    ltp[w][16 + row][0 * 16 + ln] = c10[r];
    ltp[w][16 + row][1 * 16 + ln] = c11[r];
    ltp[w][16 + row][2 * 16 + ln] = c12[r];
    ltp[w][16 + row][3 * 16 + ln] = c13[r];
  }
  __syncthreads();

  // ---------------- softmax + top-2 (rounds 5-8 epilogue) ----------------
#pragma unroll
  for (int i = 0; i < 8; ++i) {
    const int tok = w * 8 + i;
    const float v = ltp[0][tok][l] + ltp[1][tok][l] + ltp[2][tok][l] + ltp[3][tok][l];
    float bv = v; int bi = l;
    for (int off = 32; off; off >>= 1) {
      const float ov = __shfl_xor(bv, off);
      const int oi = __shfl_xor(bi, off);
      if (ov > bv || (ov == bv && oi < bi)) { bv = ov; bi = oi; }
    }
    const int i1 = bi;
    const float m1 = bv;
    float cv = (l == i1) ? -3.402823466e38f : v;
    int ci = l;
    for (int off = 32; off; off >>= 1) {
      const float ov = __shfl_xor(cv, off);
      const int oi = __shfl_xor(ci, off);
      if (ov > cv || (ov == cv && oi < ci)) { cv = ov; ci = oi; }
    }
    const float e = __expf(v - m1);
    float s = e;
    for (int off = 32; off; off >>= 1) s += __shfl_xor(s, off);
    logits[(size_t)(tb + tok) * 64 + l] = v;
    y[(size_t)(tb + tok) * 64 + l] = (l == i1 || l == ci) ? (e / s) : 0.0f;
  }
}

// ---------------- launcher ------------------------------------------------
extern "C" void kernel_launch(void* const* d_in, const int* in_sizes, int n_in,
                              void* d_out, int out_size, void* d_ws, size_t ws_size,
                              hipStream_t stream) {
  (void)in_sizes; (void)n_in; (void)out_size; (void)ws_size;
  const float* x = (const float*)d_in[0];
  const float* W = (const float*)d_in[1];
  float* out = (float*)d_out;
  float* yout = out;                 // [16384,64]
  float* logits = out + 1048576;     // [16384,64]
  __bf16* wsW = (__bf16*)d_ws;       // 1 MB frag-ready bf16 hi/lo W

  k_prep_w<<<128, 256, 0, stream>>>(W, wsW);
  k_gate<<<512, 256, 0, stream>>>(x, wsW, yout, logits);
}